// Round 2
// baseline (414.844 us; speedup 1.0000x reference)
//
// LinOSS layer (B=16, N=4096, q=256) on MI355X gfx950.
// Round 8: LDS-FREE GEMMs. K=256 is too short for any barriered LDS pipeline
// (8 K-steps cannot amortize the vmcnt(0) barrier drain); meanwhile the
// B-operand (256x256 weight) is L1/L2-resident and the A-operand has no
// K-reuse. So both GEMMs load MFMA fragments DIRECTLY from global:
//   A-frag: lane ln,quad reads 16B at row(m0+mi*16+ln), k0+quad*8 (coalesced
//           64B per 4 lanes); u is read fp32 and converted in-register.
//   B-frag: same pattern on the bf16 weight (prepw converts 3 weights once).
// No LDS, no __syncthreads, full K-unroll -> compiler hoists loads deeply.
//   prepw:  W_B/W_C/W_D -> bf16 (0.77 MB, ~3 us)
//   gemm1d: u(f32) @ WBb^T -> fx = dt*s*Bu (fp32, y-region of d_out)
//   scan:   3-phase chunked recurrence, CHUNKS=64 (4 blocks/CU), fp32;
//           scan3 also emits y as bf16 into ws for gemm2d
//   gemm2d: yb(bf16) @ WCb^T + u(f32) @ WDb^T -> erf-GELU -> g*sig(g)+u -> out0
// Old fp32-LDS-staging GEMMs retained as fallback for small ws_size.

#include <hip/hip_runtime.h>
#include <hip/hip_bf16.h>
#include <cstdint>

typedef __bf16 bf16_t;
typedef __bf16 bf16x8 __attribute__((ext_vector_type(8)));
typedef float f32x4 __attribute__((ext_vector_type(4)));

#define B_SZ 16
#define N_SZ 4096
#define Q_SZ 256
#define M_TOT (B_SZ * N_SZ) /* 65536 */
#define DT (1.0f / 4096.0f)
#define LDST 40 /* fallback-path LDS row stride in bf16 elems */
#define CHUNKS 64
#define LOG2_CLEN 6
#define CLEN (N_SZ / CHUNKS) /* 64 */
#define PF 8

// ---------------- shared helpers ----------------

// load 8 contiguous fp32, convert to bf16x8 (RNE)
__device__ __forceinline__ bf16x8 load8f(const float* p) {
  const float4 v0 = *(const float4*)p;
  const float4 v1 = *(const float4*)(p + 4);
  bf16x8 v;
  v[0] = (bf16_t)v0.x; v[1] = (bf16_t)v0.y; v[2] = (bf16_t)v0.z; v[3] = (bf16_t)v0.w;
  v[4] = (bf16_t)v1.x; v[5] = (bf16_t)v1.y; v[6] = (bf16_t)v1.z; v[7] = (bf16_t)v1.w;
  return v;
}

// ---------------- LDS-free GEMM path ----------------
// One full K=256 pass for one wave's 64x64 output tile.
// A_F32: A is fp32 (convert in-register); else A is bf16.
template <bool A_F32>
__device__ __forceinline__ void kpass(const void* __restrict__ Aptr,
                                      const bf16_t* __restrict__ Bw,
                                      int aRow0, int bRow0, int ln, int quad,
                                      f32x4 acc[4][4]) {
#pragma unroll
  for (int k0 = 0; k0 < Q_SZ; k0 += 32) {
    bf16x8 af[4], bv[4];
#pragma unroll
    for (int i = 0; i < 4; ++i) {
      if constexpr (A_F32) {
        af[i] = load8f((const float*)Aptr +
                       (size_t)(aRow0 + i * 16 + ln) * Q_SZ + k0 + quad * 8);
      } else {
        af[i] = *(const bf16x8*)((const bf16_t*)Aptr +
                                 (size_t)(aRow0 + i * 16 + ln) * Q_SZ + k0 + quad * 8);
      }
      bv[i] = *(const bf16x8*)(Bw + (size_t)(bRow0 + i * 16 + ln) * Q_SZ + k0 + quad * 8);
    }
#pragma unroll
    for (int mi = 0; mi < 4; ++mi)
#pragma unroll
      for (int ni = 0; ni < 4; ++ni)
        acc[mi][ni] = __builtin_amdgcn_mfma_f32_16x16x32_bf16(af[mi], bv[ni],
                                                              acc[mi][ni], 0, 0, 0);
  }
}

// prepw: WB/WC/WD (256x256 fp32) -> bf16
__global__ __launch_bounds__(256) void prepw_kernel(
    const float* __restrict__ WB, const float* __restrict__ WC,
    const float* __restrict__ WD, bf16_t* __restrict__ WBb,
    bf16_t* __restrict__ WCb, bf16_t* __restrict__ WDb) {
  const int g = blockIdx.x * 256 + threadIdx.x; // 0..24575 chunks of 8
  const int w = g >> 13;                        // 8192 chunks per weight
  const int idx = g & 8191;
  const float* src = (w == 0) ? WB : (w == 1) ? WC : WD;
  bf16_t* dst = (w == 0) ? WBb : (w == 1) ? WCb : WDb;
  *(bf16x8*)(dst + (size_t)idx * 8) = load8f(src + (size_t)idx * 8);
}

// gemm1d: fx[m,p] = dt*s_p*(sum_q u[m,q] WBb[p,q] + bB[p])
__global__ __launch_bounds__(256, 3) void gemm1d_kernel(
    const float* __restrict__ u, const bf16_t* __restrict__ WBb,
    const float* __restrict__ a, const float* __restrict__ bB,
    float* __restrict__ fx) {
  const int t = threadIdx.x;
  const int bid = blockIdx.x;
  const int swz = (bid & 7) * 128 + (bid >> 3); // bijective XCD swizzle, nwg=1024
  const int m0 = (swz >> 1) * 128, n0 = (swz & 1) * 128;
  const int lane = t & 63, ln = lane & 15, quad = lane >> 4;
  const int wave = t >> 6;
  const int wm = (wave & 1) * 64, wn = (wave >> 1) * 64;
  f32x4 acc[4][4] = {};
  kpass<true>(u, WBb, m0 + wm, n0 + wn, ln, quad, acc);
#pragma unroll
  for (int ni = 0; ni < 4; ++ni) {
    const int gp = n0 + wn + ni * 16 + ln; // D: col = lane&15
    const float av = a[gp];
    const float s = 1.0f / (1.0f + DT * DT * av);
    const float sc = DT * s;
    const float bb = bB[gp];
#pragma unroll
    for (int mi = 0; mi < 4; ++mi) {
      const int gm = m0 + wm + mi * 16 + quad * 4; // D: row = quad*4+reg
#pragma unroll
      for (int r2 = 0; r2 < 4; ++r2)
        fx[(size_t)(gm + r2) * Q_SZ + gp] = sc * (acc[mi][ni][r2] + bb);
    }
  }
}

// gemm2d: x = yb@WCb^T + u@WDb^T + bC + bD; g = gelu_erf(x); out0 = g*sig(g)+u
__global__ __launch_bounds__(256, 3) void gemm2d_kernel(
    const bf16_t* __restrict__ yb, const bf16_t* __restrict__ WCb,
    const float* __restrict__ u, const bf16_t* __restrict__ WDb,
    const float* __restrict__ bC, const float* __restrict__ bD,
    float* __restrict__ out0) {
  const int t = threadIdx.x;
  const int bid = blockIdx.x;
  const int swz = (bid & 7) * 128 + (bid >> 3);
  const int m0 = (swz >> 1) * 128, n0 = (swz & 1) * 128;
  const int lane = t & 63, ln = lane & 15, quad = lane >> 4;
  const int wave = t >> 6;
  const int wm = (wave & 1) * 64, wn = (wave >> 1) * 64;
  f32x4 acc[4][4] = {};
  kpass<false>(yb, WCb, m0 + wm, n0 + wn, ln, quad, acc);
  kpass<true>(u, WDb, m0 + wm, n0 + wn, ln, quad, acc);
#pragma unroll
  for (int ni = 0; ni < 4; ++ni) {
    const int gp = n0 + wn + ni * 16 + ln;
    const float bias = bC[gp] + bD[gp];
#pragma unroll
    for (int mi = 0; mi < 4; ++mi) {
      const int gm = m0 + wm + mi * 16 + quad * 4;
#pragma unroll
      for (int r2 = 0; r2 < 4; ++r2) {
        const float x = acc[mi][ni][r2] + bias;
        const float g = 0.5f * x * (1.0f + erff(x * 0.70710678118654752f));
        const float sg = 1.0f / (1.0f + __expf(-g));
        const float uu = u[(size_t)(gm + r2) * Q_SZ + gp];
        out0[(size_t)(gm + r2) * Q_SZ + gp] = fmaf(g, sg, uu);
      }
    }
  }
}

// ---------------- scan (3-phase chunked, CHUNKS=64) ----------------

__global__ __launch_bounds__(256) void scan1_kernel(
    const float* __restrict__ fx, const float* __restrict__ a,
    float* __restrict__ ex, float* __restrict__ ez) {
  const int g = blockIdx.x * 256 + threadIdx.x; // 0..262143
  const int p = g & 255, c = (g >> 8) & (CHUNKS - 1), b = g >> 14;
  const float av = a[p];
  const float s = 1.0f / (1.0f + DT * DT * av);
  const float dsa = DT * s * av, dss = DT * s;
  float x = 0.f, z = 0.f;
  const float* fp = fx + ((size_t)b * N_SZ + c * CLEN) * Q_SZ + p;
  float buf[PF], nbuf[PF];
#pragma unroll
  for (int j = 0; j < PF; ++j) buf[j] = fp[(size_t)j * Q_SZ];
  for (int n = 0; n < CLEN; n += PF) {
    if (n + PF < CLEN) {
#pragma unroll
      for (int j = 0; j < PF; ++j) nbuf[j] = fp[(size_t)(n + PF + j) * Q_SZ];
    }
#pragma unroll
    for (int j = 0; j < PF; ++j) {
      const float f = buf[j];
      const float xn = fmaf(s, x, fmaf(-dsa, z, f));
      const float zn = fmaf(dss, x, fmaf(s, z, DT * f));
      x = xn; z = zn;
    }
#pragma unroll
    for (int j = 0; j < PF; ++j) buf[j] = nbuf[j];
  }
  ex[g] = x; ez[g] = z;
}

__global__ __launch_bounds__(256) void scan2_kernel(
    const float* __restrict__ a, const float* __restrict__ ex,
    const float* __restrict__ ez, float* __restrict__ ix, float* __restrict__ iz) {
  const int g = blockIdx.x * 256 + threadIdx.x; // 0..4095
  const int p = g & 255, b = g >> 8;
  const float av = a[p];
  const float s = 1.0f / (1.0f + DT * DT * av);
  float m00 = s, m01 = -DT * s * av, m10 = DT * s, m11 = s;
#pragma unroll
  for (int i = 0; i < LOG2_CLEN; ++i) { // M^(2^LOG2_CLEN) = M^CLEN
    const float a00 = fmaf(m00, m00, m01 * m10);
    const float a01 = m01 * (m00 + m11);
    const float a10 = m10 * (m00 + m11);
    const float a11 = fmaf(m11, m11, m01 * m10);
    m00 = a00; m01 = a01; m10 = a10; m11 = a11;
  }
  float x = 0.f, z = 0.f;
  for (int c = 0; c < CHUNKS; ++c) {
    const size_t idx = ((size_t)b * CHUNKS + c) * Q_SZ + p;
    ix[idx] = x; iz[idx] = z;
    const float xn = fmaf(m00, x, fmaf(m01, z, ex[idx]));
    const float zn = fmaf(m10, x, fmaf(m11, z, ez[idx]));
    x = xn; z = zn;
  }
}

// phase 3: rescan from true initial states; y overwrites fx; optional bf16 copy
__global__ __launch_bounds__(256) void scan3_kernel(
    const float* __restrict__ a, const float* __restrict__ ix,
    const float* __restrict__ iz, float* __restrict__ yf,
    bf16_t* __restrict__ yb) {
  const int g = blockIdx.x * 256 + threadIdx.x;
  const int p = g & 255, c = (g >> 8) & (CHUNKS - 1), b = g >> 14;
  const float av = a[p];
  const float s = 1.0f / (1.0f + DT * DT * av);
  const float dsa = DT * s * av, dss = DT * s;
  float x = ix[g], z = iz[g];
  const size_t base = ((size_t)b * N_SZ + c * CLEN) * Q_SZ + p;
  float* yp = yf + base;
  bf16_t* ybp = yb ? yb + base : nullptr;
  float buf[PF], nbuf[PF];
#pragma unroll
  for (int j = 0; j < PF; ++j) buf[j] = yp[(size_t)j * Q_SZ];
  for (int n = 0; n < CLEN; n += PF) {
    if (n + PF < CLEN) {
#pragma unroll
      for (int j = 0; j < PF; ++j) nbuf[j] = yp[(size_t)(n + PF + j) * Q_SZ];
    }
#pragma unroll
    for (int j = 0; j < PF; ++j) {
      const float f = buf[j];
      const float xn = fmaf(s, x, fmaf(-dsa, z, f));
      const float zn = fmaf(dss, x, fmaf(s, z, DT * f));
      x = xn; z = zn;
      yp[(size_t)(n + j) * Q_SZ] = zn;
      if (yb) ybp[(size_t)(n + j) * Q_SZ] = (bf16_t)zn;
    }
#pragma unroll
    for (int j = 0; j < PF; ++j) buf[j] = nbuf[j];
  }
}

__global__ __launch_bounds__(256) void scan_mono_kernel(
    const float* __restrict__ a, float* __restrict__ yf) {
  const int g = blockIdx.x * 256 + threadIdx.x; // 0..4095
  const int p = g & 255, b = g >> 8;
  const float av = a[p];
  const float s = 1.0f / (1.0f + DT * DT * av);
  const float dsa = DT * s * av, dss = DT * s;
  float x = 0.f, z = 0.f;
  float* yp = yf + (size_t)b * N_SZ * Q_SZ + p;
  float buf[PF], nbuf[PF];
#pragma unroll
  for (int j = 0; j < PF; ++j) buf[j] = yp[(size_t)j * Q_SZ];
  for (int n = 0; n < N_SZ; n += PF) {
    if (n + PF < N_SZ) {
#pragma unroll
      for (int j = 0; j < PF; ++j) nbuf[j] = yp[(size_t)(n + PF + j) * Q_SZ];
    }
#pragma unroll
    for (int j = 0; j < PF; ++j) {
      const float f = buf[j];
      const float xn = fmaf(s, x, fmaf(-dsa, z, f));
      const float zn = fmaf(dss, x, fmaf(s, z, DT * f));
      x = xn; z = zn;
      yp[(size_t)(n + j) * Q_SZ] = zn;
    }
#pragma unroll
    for (int j = 0; j < PF; ++j) buf[j] = nbuf[j];
  }
}

// ---------------- old fp32-LDS-staging GEMM path (fallback) ----------------

__device__ __forceinline__ void kloop(const float* __restrict__ Ap,
                                      const float* __restrict__ Bp,
                                      int m0, int n0, int t,
                                      bf16_t* As, bf16_t* Bs, f32x4 acc[4][4]) {
  const int r = t >> 2, cc = t & 3;
  const int lane = t & 63, ln = lane & 15, quad = lane >> 4;
  const int wave = t >> 6;
  const int wm = (wave & 1) * 64, wn = (wave >> 1) * 64;

  for (int k0 = 0; k0 < Q_SZ; k0 += 32) {
#pragma unroll
    for (int i = 0; i < 2; ++i) {
      const int row = r + i * 64;
      const int col = k0 + cc * 8;
      *(bf16x8*)(As + row * LDST + cc * 8) =
          load8f(Ap + (size_t)(m0 + row) * Q_SZ + col);
      *(bf16x8*)(Bs + row * LDST + cc * 8) =
          load8f(Bp + (size_t)(n0 + row) * Q_SZ + col);
    }
    __syncthreads();
    bf16x8 af[4], bv[4];
#pragma unroll
    for (int mi = 0; mi < 4; ++mi) {
      af[mi] = *(const bf16x8*)(As + (wm + mi * 16 + ln) * LDST + quad * 8);
      bv[mi] = *(const bf16x8*)(Bs + (wn + mi * 16 + ln) * LDST + quad * 8);
    }
#pragma unroll
    for (int mi = 0; mi < 4; ++mi)
#pragma unroll
      for (int ni = 0; ni < 4; ++ni)
        acc[mi][ni] = __builtin_amdgcn_mfma_f32_16x16x32_bf16(af[mi], bv[ni],
                                                              acc[mi][ni], 0, 0, 0);
    __syncthreads();
  }
}

__global__ __launch_bounds__(256) void gemm1_kernel(
    const float* __restrict__ u, const float* __restrict__ WB,
    const float* __restrict__ a, const float* __restrict__ bB,
    float* __restrict__ fx) {
  __shared__ __align__(16) bf16_t As[128 * LDST];
  __shared__ __align__(16) bf16_t Bs[128 * LDST];
  const int t = threadIdx.x;
  const int m0 = blockIdx.x * 128, n0 = blockIdx.y * 128;
  f32x4 acc[4][4] = {};
  kloop(u, WB, m0, n0, t, As, Bs, acc);

  const int lane = t & 63, ln = lane & 15, quad = lane >> 4;
  const int wave = t >> 6;
  const int wm = (wave & 1) * 64, wn = (wave >> 1) * 64;
#pragma unroll
  for (int ni = 0; ni < 4; ++ni) {
    const int gp = n0 + wn + ni * 16 + ln;
    const float av = a[gp];
    const float s = 1.0f / (1.0f + DT * DT * av);
    const float sc = DT * s;
    const float bb = bB[gp];
#pragma unroll
    for (int mi = 0; mi < 4; ++mi) {
      const int gm = m0 + wm + mi * 16 + quad * 4;
#pragma unroll
      for (int r2 = 0; r2 < 4; ++r2)
        fx[(size_t)(gm + r2) * Q_SZ + gp] = sc * (acc[mi][ni][r2] + bb);
    }
  }
}

__global__ __launch_bounds__(256) void gemm2_kernel(
    const float* __restrict__ y, const float* __restrict__ WC,
    const float* __restrict__ u, const float* __restrict__ WD,
    const float* __restrict__ bC, const float* __restrict__ bD,
    float* __restrict__ out0) {
  __shared__ __align__(16) bf16_t As[128 * LDST];
  __shared__ __align__(16) bf16_t Bs[128 * LDST];
  const int t = threadIdx.x;
  const int m0 = blockIdx.x * 128, n0 = blockIdx.y * 128;
  f32x4 acc[4][4] = {};
  kloop(y, WC, m0, n0, t, As, Bs, acc);
  kloop(u, WD, m0, n0, t, As, Bs, acc);

  const int lane = t & 63, ln = lane & 15, quad = lane >> 4;
  const int wave = t >> 6;
  const int wm = (wave & 1) * 64, wn = (wave >> 1) * 64;
#pragma unroll
  for (int ni = 0; ni < 4; ++ni) {
    const int gp = n0 + wn + ni * 16 + ln;
    const float bias = bC[gp] + bD[gp];
#pragma unroll
    for (int mi = 0; mi < 4; ++mi) {
      const int gm = m0 + wm + mi * 16 + quad * 4;
#pragma unroll
      for (int r2 = 0; r2 < 4; ++r2) {
        const float x = acc[mi][ni][r2] + bias;
        const float g = 0.5f * x * (1.0f + erff(x * 0.70710678118654752f));
        const float sg = 1.0f / (1.0f + __expf(-g));
        const float uu = u[(size_t)(gm + r2) * Q_SZ + gp];
        out0[(size_t)(gm + r2) * Q_SZ + gp] = fmaf(g, sg, uu);
      }
    }
  }
}

// ---------------- launcher ----------------

extern "C" void kernel_launch(void* const* d_in, const int* in_sizes, int n_in,
                              void* d_out, int out_size, void* d_ws, size_t ws_size,
                              hipStream_t stream) {
  const float* u  = (const float*)d_in[0];
  const float* a  = (const float*)d_in[1];
  const float* WB = (const float*)d_in[2];
  const float* bB = (const float*)d_in[3];
  const float* WC = (const float*)d_in[4];
  const float* bC = (const float*)d_in[5];
  const float* WD = (const float*)d_in[6];
  const float* bD = (const float*)d_in[7];

  float* out0 = (float*)d_out;                // first 16.7M fp32: out
  float* yreg = out0 + (size_t)M_TOT * Q_SZ;  // second 16.7M fp32: fx -> y

  const size_t UB_ELEMS = (size_t)M_TOT * Q_SZ;  // 16,777,216
  const size_t W_ELEMS = (size_t)Q_SZ * Q_SZ;    // 65,536
  const size_t state_bytes =
      4 * (size_t)B_SZ * CHUNKS * Q_SZ * sizeof(float); // 4 MiB (CHUNKS=64)
  const size_t need_full =
      (UB_ELEMS + 3 * W_ELEMS) * sizeof(bf16_t) + state_bytes; // ~38 MB

  if (ws_size >= need_full) {
    bf16_t* yb  = (bf16_t*)d_ws;
    bf16_t* WBb = yb + UB_ELEMS;
    bf16_t* WCb = WBb + W_ELEMS;
    bf16_t* WDb = WCb + W_ELEMS;
    float* ex = (float*)(WDb + W_ELEMS);
    float* ez = ex + (size_t)B_SZ * CHUNKS * Q_SZ;
    float* ix = ez + (size_t)B_SZ * CHUNKS * Q_SZ;
    float* iz = ix + (size_t)B_SZ * CHUNKS * Q_SZ;

    prepw_kernel<<<96, 256, 0, stream>>>(WB, WC, WD, WBb, WCb, WDb);
    gemm1d_kernel<<<1024, 256, 0, stream>>>(u, WBb, a, bB, yreg);
    scan1_kernel<<<1024, 256, 0, stream>>>(yreg, a, ex, ez);
    scan2_kernel<<<16, 256, 0, stream>>>(a, ex, ez, ix, iz);
    scan3_kernel<<<1024, 256, 0, stream>>>(a, ix, iz, yreg, yb);
    gemm2d_kernel<<<1024, 256, 0, stream>>>(yb, WCb, u, WDb, bC, bD, out0);
  } else {
    dim3 gg(M_TOT / 128, Q_SZ / 128);
    gemm1_kernel<<<gg, 256, 0, stream>>>(u, WB, a, bB, yreg);
    if (ws_size >= state_bytes) {
      float* ex = (float*)d_ws;
      float* ez = ex + (size_t)B_SZ * CHUNKS * Q_SZ;
      float* ix = ez + (size_t)B_SZ * CHUNKS * Q_SZ;
      float* iz = ix + (size_t)B_SZ * CHUNKS * Q_SZ;
      scan1_kernel<<<1024, 256, 0, stream>>>(yreg, a, ex, ez);
      scan2_kernel<<<16, 256, 0, stream>>>(a, ex, ez, ix, iz);
      scan3_kernel<<<1024, 256, 0, stream>>>(a, ix, iz, yreg, (bf16_t*)nullptr);
    } else {
      scan_mono_kernel<<<16, 256, 0, stream>>>(a, yreg);
    }
    gemm2_kernel<<<gg, 256, 0, stream>>>(yreg, WC, u, WD, bC, bD, out0);
  }
}

// Round 3
// 330.995 us; speedup vs baseline: 1.2533x; 1.2533x over previous
//
// LinOSS layer (B=16, N=4096, q=256) on MI355X gfx950.
// Round 9: PACKED-FRAGMENT GEMMs (no LDS, no barriers, lane-linear loads).
// R8 lesson: direct fragment loads from row-major operands are lane-scattered
// (16 rows per wave-load -> 16 line-requests) and throttle on address/request
// throughput (MfmaUtil 4%, VALUBusy 17%, HBM 13% -- nothing else busy).
// Fix: store ALL GEMM operands in packed MFMA-fragment order:
//   chunk[(tm*8+tk)*64 + lane] = 16B of row tm*16+(lane&15),
//                                cols tk*32+(lane>>4)*8 .. +7   (bf16)
// so every fragment load is 64 lanes x consecutive 16B = 1KB coalesced.
//   prep:   u -> ubP (packed bf16), W_B/W_C/W_D -> packed bf16
//   gemm1p: ubP @ WBbP^T -> fx = dt*s*Bu (fp32 row-major, y region)
//   scan:   3-phase chunked recurrence (CHUNKS=64), fp32, in place;
//           scan3 also writes y packed-bf16 (ybP) for gemm2p
//   gemm2p: ybP@WCbP^T + ubP@WDbP^T (fused per-tk) -> erf-GELU ->
//           g*sigmoid(g) + u -> out0
// Old fp32-LDS-staging GEMM path retained as fallback for small ws_size.

#include <hip/hip_runtime.h>
#include <hip/hip_bf16.h>
#include <cstdint>

typedef __bf16 bf16_t;
typedef __bf16 bf16x8 __attribute__((ext_vector_type(8)));
typedef float f32x4 __attribute__((ext_vector_type(4)));

#define B_SZ 16
#define N_SZ 4096
#define Q_SZ 256
#define M_TOT (B_SZ * N_SZ) /* 65536 */
#define DT (1.0f / 4096.0f)
#define LDST 40 /* fallback-path LDS row stride in bf16 elems */
#define CHUNKS 64
#define LOG2_CLEN 6
#define CLEN (N_SZ / CHUNKS) /* 64 */
#define PF 8

// ---------------- shared helpers ----------------

// load 8 contiguous fp32, convert to bf16x8 (RNE)
__device__ __forceinline__ bf16x8 load8f(const float* p) {
  const float4 v0 = *(const float4*)p;
  const float4 v1 = *(const float4*)(p + 4);
  bf16x8 v;
  v[0] = (bf16_t)v0.x; v[1] = (bf16_t)v0.y; v[2] = (bf16_t)v0.z; v[3] = (bf16_t)v0.w;
  v[4] = (bf16_t)v1.x; v[5] = (bf16_t)v1.y; v[6] = (bf16_t)v1.z; v[7] = (bf16_t)v1.w;
  return v;
}

// packed-fragment element offset of chunk (tm, tk, lane)
__device__ __forceinline__ int pidx(int tm, int tk, int lane) {
  return ((tm * 8 + tk) * 64 + lane) * 8;
}

// ---------------- packed-fragment GEMM path ----------------

// single-A kpass: full K=256 for one wave's 64x64 tile
__device__ __forceinline__ void kpassP(const bf16_t* __restrict__ A,
                                       const bf16_t* __restrict__ Bw,
                                       int tmA, int tnB, int lane,
                                       f32x4 acc[4][4]) {
#pragma unroll
  for (int tk = 0; tk < 8; ++tk) {
    bf16x8 af[4], bv[4];
#pragma unroll
    for (int i = 0; i < 4; ++i) {
      af[i] = *(const bf16x8*)(A + pidx(tmA + i, tk, lane));
      bv[i] = *(const bf16x8*)(Bw + pidx(tnB + i, tk, lane));
    }
#pragma unroll
    for (int mi = 0; mi < 4; ++mi)
#pragma unroll
      for (int ni = 0; ni < 4; ++ni)
        acc[mi][ni] = __builtin_amdgcn_mfma_f32_16x16x32_bf16(af[mi], bv[ni],
                                                              acc[mi][ni], 0, 0, 0);
  }
}

// fused dual kpass: acc += A1@B1^T + A2@B2^T, interleaved per tk (16-deep loads)
__device__ __forceinline__ void kpass2P(const bf16_t* __restrict__ A1,
                                        const bf16_t* __restrict__ B1,
                                        const bf16_t* __restrict__ A2,
                                        const bf16_t* __restrict__ B2,
                                        int tmA, int tnB, int lane,
                                        f32x4 acc[4][4]) {
#pragma unroll
  for (int tk = 0; tk < 8; ++tk) {
    bf16x8 a1[4], b1[4], a2[4], b2[4];
#pragma unroll
    for (int i = 0; i < 4; ++i) {
      a1[i] = *(const bf16x8*)(A1 + pidx(tmA + i, tk, lane));
      b1[i] = *(const bf16x8*)(B1 + pidx(tnB + i, tk, lane));
      a2[i] = *(const bf16x8*)(A2 + pidx(tmA + i, tk, lane));
      b2[i] = *(const bf16x8*)(B2 + pidx(tnB + i, tk, lane));
    }
#pragma unroll
    for (int mi = 0; mi < 4; ++mi)
#pragma unroll
      for (int ni = 0; ni < 4; ++ni)
        acc[mi][ni] = __builtin_amdgcn_mfma_f32_16x16x32_bf16(a1[mi], b1[ni],
                                                              acc[mi][ni], 0, 0, 0);
#pragma unroll
    for (int mi = 0; mi < 4; ++mi)
#pragma unroll
      for (int ni = 0; ni < 4; ++ni)
        acc[mi][ni] = __builtin_amdgcn_mfma_f32_16x16x32_bf16(a2[mi], b2[ni],
                                                              acc[mi][ni], 0, 0, 0);
  }
}

// prep: u (65536x256 f32) -> packed bf16; WB/WC/WD (256x256 f32) -> packed bf16
__global__ __launch_bounds__(256) void prep_kernel(
    const float* __restrict__ u, const float* __restrict__ WB,
    const float* __restrict__ WC, const float* __restrict__ WD,
    bf16_t* __restrict__ ubP, bf16_t* __restrict__ WBbP,
    bf16_t* __restrict__ WCbP, bf16_t* __restrict__ WDbP) {
  const int g = blockIdx.x * 256 + threadIdx.x;
  const int UC = (M_TOT * Q_SZ) / 8; // 2,097,152 chunks
  const float* src;
  bf16_t* dst;
  int cidx;
  if (g < UC) {
    src = u; dst = ubP; cidx = g;
  } else {
    const int h = g - UC; // 0..24575
    const int w = h >> 13;
    cidx = h & 8191;
    src = (w == 0) ? WB : (w == 1) ? WC : WD;
    dst = (w == 0) ? WBbP : (w == 1) ? WCbP : WDbP;
  }
  const int lane = cidx & 63, tk = (cidx >> 6) & 7, tm = cidx >> 9;
  const int row = tm * 16 + (lane & 15);
  const int col = tk * 32 + (lane >> 4) * 8;
  *(bf16x8*)(dst + (size_t)cidx * 8) = load8f(src + (size_t)row * Q_SZ + col);
}

// gemm1p: fx[m,p] = dt*s_p*(sum_q u[m,q] WB[p,q] + bB[p])
__global__ __launch_bounds__(256, 2) void gemm1p_kernel(
    const bf16_t* __restrict__ ubP, const bf16_t* __restrict__ WBbP,
    const float* __restrict__ a, const float* __restrict__ bB,
    float* __restrict__ fx) {
  const int t = threadIdx.x;
  const int bid = blockIdx.x;
  const int swz = (bid & 7) * 128 + (bid >> 3); // bijective XCD swizzle, nwg=1024
  const int m0 = (swz >> 1) * 128, n0 = (swz & 1) * 128;
  const int lane = t & 63, ln = lane & 15, quad = lane >> 4;
  const int wave = t >> 6;
  const int wm = (wave & 1) * 64, wn = (wave >> 1) * 64;
  f32x4 acc[4][4] = {};
  kpassP(ubP, WBbP, (m0 + wm) >> 4, (n0 + wn) >> 4, lane, acc);
#pragma unroll
  for (int ni = 0; ni < 4; ++ni) {
    const int gp = n0 + wn + ni * 16 + ln; // D: col = lane&15
    const float av = a[gp];
    const float s = 1.0f / (1.0f + DT * DT * av);
    const float sc = DT * s;
    const float bb = bB[gp];
#pragma unroll
    for (int mi = 0; mi < 4; ++mi) {
      const int gm = m0 + wm + mi * 16 + quad * 4; // D: row = quad*4+reg
#pragma unroll
      for (int r2 = 0; r2 < 4; ++r2)
        fx[(size_t)(gm + r2) * Q_SZ + gp] = sc * (acc[mi][ni][r2] + bb);
    }
  }
}

// gemm2p: x = y@WC^T + u@WD^T + bC + bD; g = gelu_erf(x); out0 = g*sig(g)+u
__global__ __launch_bounds__(256, 2) void gemm2p_kernel(
    const bf16_t* __restrict__ ybP, const bf16_t* __restrict__ WCbP,
    const bf16_t* __restrict__ ubP, const bf16_t* __restrict__ WDbP,
    const float* __restrict__ u, const float* __restrict__ bC,
    const float* __restrict__ bD, float* __restrict__ out0) {
  const int t = threadIdx.x;
  const int bid = blockIdx.x;
  const int swz = (bid & 7) * 128 + (bid >> 3);
  const int m0 = (swz >> 1) * 128, n0 = (swz & 1) * 128;
  const int lane = t & 63, ln = lane & 15, quad = lane >> 4;
  const int wave = t >> 6;
  const int wm = (wave & 1) * 64, wn = (wave >> 1) * 64;
  f32x4 acc[4][4] = {};
  kpass2P(ybP, WCbP, ubP, WDbP, (m0 + wm) >> 4, (n0 + wn) >> 4, lane, acc);
#pragma unroll
  for (int ni = 0; ni < 4; ++ni) {
    const int gp = n0 + wn + ni * 16 + ln;
    const float bias = bC[gp] + bD[gp];
#pragma unroll
    for (int mi = 0; mi < 4; ++mi) {
      const int gm = m0 + wm + mi * 16 + quad * 4;
#pragma unroll
      for (int r2 = 0; r2 < 4; ++r2) {
        const float x = acc[mi][ni][r2] + bias;
        const float g = 0.5f * x * (1.0f + erff(x * 0.70710678118654752f));
        const float sg = 1.0f / (1.0f + __expf(-g));
        const float uu = u[(size_t)(gm + r2) * Q_SZ + gp];
        out0[(size_t)(gm + r2) * Q_SZ + gp] = fmaf(g, sg, uu);
      }
    }
  }
}

// ---------------- scan (3-phase chunked, CHUNKS=64) ----------------

__global__ __launch_bounds__(256) void scan1_kernel(
    const float* __restrict__ fx, const float* __restrict__ a,
    float* __restrict__ ex, float* __restrict__ ez) {
  const int g = blockIdx.x * 256 + threadIdx.x; // 0..262143
  const int p = g & 255, c = (g >> 8) & (CHUNKS - 1), b = g >> 14;
  const float av = a[p];
  const float s = 1.0f / (1.0f + DT * DT * av);
  const float dsa = DT * s * av, dss = DT * s;
  float x = 0.f, z = 0.f;
  const float* fp = fx + ((size_t)b * N_SZ + c * CLEN) * Q_SZ + p;
  float buf[PF], nbuf[PF];
#pragma unroll
  for (int j = 0; j < PF; ++j) buf[j] = fp[(size_t)j * Q_SZ];
  for (int n = 0; n < CLEN; n += PF) {
    if (n + PF < CLEN) {
#pragma unroll
      for (int j = 0; j < PF; ++j) nbuf[j] = fp[(size_t)(n + PF + j) * Q_SZ];
    }
#pragma unroll
    for (int j = 0; j < PF; ++j) {
      const float f = buf[j];
      const float xn = fmaf(s, x, fmaf(-dsa, z, f));
      const float zn = fmaf(dss, x, fmaf(s, z, DT * f));
      x = xn; z = zn;
    }
#pragma unroll
    for (int j = 0; j < PF; ++j) buf[j] = nbuf[j];
  }
  ex[g] = x; ez[g] = z;
}

__global__ __launch_bounds__(256) void scan2_kernel(
    const float* __restrict__ a, const float* __restrict__ ex,
    const float* __restrict__ ez, float* __restrict__ ix, float* __restrict__ iz) {
  const int g = blockIdx.x * 256 + threadIdx.x; // 0..4095
  const int p = g & 255, b = g >> 8;
  const float av = a[p];
  const float s = 1.0f / (1.0f + DT * DT * av);
  float m00 = s, m01 = -DT * s * av, m10 = DT * s, m11 = s;
#pragma unroll
  for (int i = 0; i < LOG2_CLEN; ++i) { // M^(2^LOG2_CLEN) = M^CLEN
    const float a00 = fmaf(m00, m00, m01 * m10);
    const float a01 = m01 * (m00 + m11);
    const float a10 = m10 * (m00 + m11);
    const float a11 = fmaf(m11, m11, m01 * m10);
    m00 = a00; m01 = a01; m10 = a10; m11 = a11;
  }
  float x = 0.f, z = 0.f;
  for (int c = 0; c < CHUNKS; ++c) {
    const size_t idx = ((size_t)b * CHUNKS + c) * Q_SZ + p;
    ix[idx] = x; iz[idx] = z;
    const float xn = fmaf(m00, x, fmaf(m01, z, ex[idx]));
    const float zn = fmaf(m10, x, fmaf(m11, z, ez[idx]));
    x = xn; z = zn;
  }
}

// phase 3: rescan from true initial states; y (fp32) overwrites fx IN PLACE;
// optional second output: y in packed-fragment bf16 (for gemm2p)
__global__ __launch_bounds__(256) void scan3_kernel(
    const float* __restrict__ a, const float* __restrict__ ix,
    const float* __restrict__ iz, float* __restrict__ yf,
    bf16_t* __restrict__ yb) {
  const int g = blockIdx.x * 256 + threadIdx.x;
  const int p = g & 255, c = (g >> 8) & (CHUNKS - 1), b = g >> 14;
  const float av = a[p];
  const float s = 1.0f / (1.0f + DT * DT * av);
  const float dsa = DT * s * av, dss = DT * s;
  float x = ix[g], z = iz[g];
  const size_t base = ((size_t)b * N_SZ + c * CLEN) * Q_SZ + p;
  float* yp = yf + base;
  // packed-bf16 target: rows m = b*4096 + c*64 + nj, col p
  const int tk = p >> 5, quad = (p >> 3) & 3, off = p & 7;
  const size_t ybase =
      ((size_t)(b * 256 + c * 4)) * 4096 + tk * 512 + quad * 128 + off;
  float buf[PF], nbuf[PF];
#pragma unroll
  for (int j = 0; j < PF; ++j) buf[j] = yp[(size_t)j * Q_SZ];
  for (int n = 0; n < CLEN; n += PF) {
    if (n + PF < CLEN) {
#pragma unroll
      for (int j = 0; j < PF; ++j) nbuf[j] = yp[(size_t)(n + PF + j) * Q_SZ];
    }
#pragma unroll
    for (int j = 0; j < PF; ++j) {
      const float f = buf[j];
      const float xn = fmaf(s, x, fmaf(-dsa, z, f));
      const float zn = fmaf(dss, x, fmaf(s, z, DT * f));
      x = xn; z = zn;
      yp[(size_t)(n + j) * Q_SZ] = zn;
      if (yb) {
        const int nj = n + j;
        yb[ybase + ((size_t)(nj >> 4) << 12) + ((nj & 15) << 3)] = (bf16_t)zn;
      }
    }
#pragma unroll
    for (int j = 0; j < PF; ++j) buf[j] = nbuf[j];
  }
}

__global__ __launch_bounds__(256) void scan_mono_kernel(
    const float* __restrict__ a, float* __restrict__ yf) {
  const int g = blockIdx.x * 256 + threadIdx.x; // 0..4095
  const int p = g & 255, b = g >> 8;
  const float av = a[p];
  const float s = 1.0f / (1.0f + DT * DT * av);
  const float dsa = DT * s * av, dss = DT * s;
  float x = 0.f, z = 0.f;
  float* yp = yf + (size_t)b * N_SZ * Q_SZ + p;
  float buf[PF], nbuf[PF];
#pragma unroll
  for (int j = 0; j < PF; ++j) buf[j] = yp[(size_t)j * Q_SZ];
  for (int n = 0; n < N_SZ; n += PF) {
    if (n + PF < N_SZ) {
#pragma unroll
      for (int j = 0; j < PF; ++j) nbuf[j] = yp[(size_t)(n + PF + j) * Q_SZ];
    }
#pragma unroll
    for (int j = 0; j < PF; ++j) {
      const float f = buf[j];
      const float xn = fmaf(s, x, fmaf(-dsa, z, f));
      const float zn = fmaf(dss, x, fmaf(s, z, DT * f));
      x = xn; z = zn;
      yp[(size_t)(n + j) * Q_SZ] = zn;
    }
#pragma unroll
    for (int j = 0; j < PF; ++j) buf[j] = nbuf[j];
  }
}

// ---------------- old fp32-LDS-staging GEMM path (fallback) ----------------

__device__ __forceinline__ void kloop(const float* __restrict__ Ap,
                                      const float* __restrict__ Bp,
                                      int m0, int n0, int t,
                                      bf16_t* As, bf16_t* Bs, f32x4 acc[4][4]) {
  const int r = t >> 2, cc = t & 3;
  const int lane = t & 63, ln = lane & 15, quad = lane >> 4;
  const int wave = t >> 6;
  const int wm = (wave & 1) * 64, wn = (wave >> 1) * 64;

  for (int k0 = 0; k0 < Q_SZ; k0 += 32) {
#pragma unroll
    for (int i = 0; i < 2; ++i) {
      const int row = r + i * 64;
      const int col = k0 + cc * 8;
      *(bf16x8*)(As + row * LDST + cc * 8) =
          load8f(Ap + (size_t)(m0 + row) * Q_SZ + col);
      *(bf16x8*)(Bs + row * LDST + cc * 8) =
          load8f(Bp + (size_t)(n0 + row) * Q_SZ + col);
    }
    __syncthreads();
    bf16x8 af[4], bv[4];
#pragma unroll
    for (int mi = 0; mi < 4; ++mi) {
      af[mi] = *(const bf16x8*)(As + (wm + mi * 16 + ln) * LDST + quad * 8);
      bv[mi] = *(const bf16x8*)(Bs + (wn + mi * 16 + ln) * LDST + quad * 8);
    }
#pragma unroll
    for (int mi = 0; mi < 4; ++mi)
#pragma unroll
      for (int ni = 0; ni < 4; ++ni)
        acc[mi][ni] = __builtin_amdgcn_mfma_f32_16x16x32_bf16(af[mi], bv[ni],
                                                              acc[mi][ni], 0, 0, 0);
    __syncthreads();
  }
}

__global__ __launch_bounds__(256) void gemm1_kernel(
    const float* __restrict__ u, const float* __restrict__ WB,
    const float* __restrict__ a, const float* __restrict__ bB,
    float* __restrict__ fx) {
  __shared__ __align__(16) bf16_t As[128 * LDST];
  __shared__ __align__(16) bf16_t Bs[128 * LDST];
  const int t = threadIdx.x;
  const int m0 = blockIdx.x * 128, n0 = blockIdx.y * 128;
  f32x4 acc[4][4] = {};
  kloop(u, WB, m0, n0, t, As, Bs, acc);

  const int lane = t & 63, ln = lane & 15, quad = lane >> 4;
  const int wave = t >> 6;
  const int wm = (wave & 1) * 64, wn = (wave >> 1) * 64;
#pragma unroll
  for (int ni = 0; ni < 4; ++ni) {
    const int gp = n0 + wn + ni * 16 + ln;
    const float av = a[gp];
    const float s = 1.0f / (1.0f + DT * DT * av);
    const float sc = DT * s;
    const float bb = bB[gp];
#pragma unroll
    for (int mi = 0; mi < 4; ++mi) {
      const int gm = m0 + wm + mi * 16 + quad * 4;
#pragma unroll
      for (int r2 = 0; r2 < 4; ++r2)
        fx[(size_t)(gm + r2) * Q_SZ + gp] = sc * (acc[mi][ni][r2] + bb);
    }
  }
}

__global__ __launch_bounds__(256) void gemm2_kernel(
    const float* __restrict__ y, const float* __restrict__ WC,
    const float* __restrict__ u, const float* __restrict__ WD,
    const float* __restrict__ bC, const float* __restrict__ bD,
    float* __restrict__ out0) {
  __shared__ __align__(16) bf16_t As[128 * LDST];
  __shared__ __align__(16) bf16_t Bs[128 * LDST];
  const int t = threadIdx.x;
  const int m0 = blockIdx.x * 128, n0 = blockIdx.y * 128;
  f32x4 acc[4][4] = {};
  kloop(y, WC, m0, n0, t, As, Bs, acc);
  kloop(u, WD, m0, n0, t, As, Bs, acc);

  const int lane = t & 63, ln = lane & 15, quad = lane >> 4;
  const int wave = t >> 6;
  const int wm = (wave & 1) * 64, wn = (wave >> 1) * 64;
#pragma unroll
  for (int ni = 0; ni < 4; ++ni) {
    const int gp = n0 + wn + ni * 16 + ln;
    const float bias = bC[gp] + bD[gp];
#pragma unroll
    for (int mi = 0; mi < 4; ++mi) {
      const int gm = m0 + wm + mi * 16 + quad * 4;
#pragma unroll
      for (int r2 = 0; r2 < 4; ++r2) {
        const float x = acc[mi][ni][r2] + bias;
        const float g = 0.5f * x * (1.0f + erff(x * 0.70710678118654752f));
        const float sg = 1.0f / (1.0f + __expf(-g));
        const float uu = u[(size_t)(gm + r2) * Q_SZ + gp];
        out0[(size_t)(gm + r2) * Q_SZ + gp] = fmaf(g, sg, uu);
      }
    }
  }
}

// ---------------- launcher ----------------

extern "C" void kernel_launch(void* const* d_in, const int* in_sizes, int n_in,
                              void* d_out, int out_size, void* d_ws, size_t ws_size,
                              hipStream_t stream) {
  const float* u  = (const float*)d_in[0];
  const float* a  = (const float*)d_in[1];
  const float* WB = (const float*)d_in[2];
  const float* bB = (const float*)d_in[3];
  const float* WC = (const float*)d_in[4];
  const float* bC = (const float*)d_in[5];
  const float* WD = (const float*)d_in[6];
  const float* bD = (const float*)d_in[7];

  float* out0 = (float*)d_out;                // first 16.7M fp32: out
  float* yreg = out0 + (size_t)M_TOT * Q_SZ;  // second 16.7M fp32: fx -> y

  const size_t UB_ELEMS = (size_t)M_TOT * Q_SZ;  // 16,777,216
  const size_t W_ELEMS = (size_t)Q_SZ * Q_SZ;    // 65,536
  const size_t state_bytes =
      4 * (size_t)B_SZ * CHUNKS * Q_SZ * sizeof(float); // 4 MiB
  const size_t need_full =
      (2 * UB_ELEMS + 3 * W_ELEMS) * sizeof(bf16_t) + state_bytes; // ~71.5 MB

  if (ws_size >= need_full) {
    bf16_t* ubP  = (bf16_t*)d_ws;
    bf16_t* ybP  = ubP + UB_ELEMS;
    bf16_t* WBbP = ybP + UB_ELEMS;
    bf16_t* WCbP = WBbP + W_ELEMS;
    bf16_t* WDbP = WCbP + W_ELEMS;
    float* ex = (float*)(WDbP + W_ELEMS);
    float* ez = ex + (size_t)B_SZ * CHUNKS * Q_SZ;
    float* ix = ez + (size_t)B_SZ * CHUNKS * Q_SZ;
    float* iz = ix + (size_t)B_SZ * CHUNKS * Q_SZ;

    prep_kernel<<<8288, 256, 0, stream>>>(u, WB, WC, WD, ubP, WBbP, WCbP, WDbP);
    gemm1p_kernel<<<1024, 256, 0, stream>>>(ubP, WBbP, a, bB, yreg);
    scan1_kernel<<<1024, 256, 0, stream>>>(yreg, a, ex, ez);
    scan2_kernel<<<16, 256, 0, stream>>>(a, ex, ez, ix, iz);
    scan3_kernel<<<1024, 256, 0, stream>>>(a, ix, iz, yreg, ybP);
    gemm2p_kernel<<<1024, 256, 0, stream>>>(ybP, WCbP, ubP, WDbP, u, bC, bD, out0);
  } else {
    dim3 gg(M_TOT / 128, Q_SZ / 128);
    gemm1_kernel<<<gg, 256, 0, stream>>>(u, WB, a, bB, yreg);
    if (ws_size >= state_bytes) {
      float* ex = (float*)d_ws;
      float* ez = ex + (size_t)B_SZ * CHUNKS * Q_SZ;
      float* ix = ez + (size_t)B_SZ * CHUNKS * Q_SZ;
      float* iz = ix + (size_t)B_SZ * CHUNKS * Q_SZ;
      scan1_kernel<<<1024, 256, 0, stream>>>(yreg, a, ex, ez);
      scan2_kernel<<<16, 256, 0, stream>>>(a, ex, ez, ix, iz);
      scan3_kernel<<<1024, 256, 0, stream>>>(a, ix, iz, yreg, (bf16_t*)nullptr);
    } else {
      scan_mono_kernel<<<16, 256, 0, stream>>>(a, yreg);
    }
    gemm2_kernel<<<gg, 256, 0, stream>>>(yreg, WC, u, WD, bC, bD, out0);
  }
}